// Round 6
// baseline (125.622 us; speedup 1.0000x reference)
//
#include <hip/hip_runtime.h>

// Geometry fixed by setup_inputs: [16, 1, 352, 1216] fp32.
#define BATCH 16
#define HH    352
#define WW    1216
#define IMG   (HH * WW)
#define QPR   (WW / 4)          // 304 quads (float4 groups) per row
#define BLOCK 320               // 5 waves; covers one full row of quads
#define NWAVE (BLOCK / 64)
#define RPB   4                 // output rows per block (and per thread)
#define SLOTSI (HH / RPB)       // 88 blocks per image, one slot each
#define PADS  128               // slots padded to 2*64 (pads zero-filled)
#define NBLK  (BATCH * SLOTSI)  // 1408 (divisible by 8)
#define NXCD  8
#define CHUNK (NBLK / NXCD)     // 176
#define NROW  (RPB + 2)         // 6 input row-slots per tensor

// Workspace (floats): [0..8191] p1s = float4[16*128] {Sm,Sp,St,0};
//                     [8192..10239] acc = float[16*128] loss partials.
#define WS_ACC_F 8192

__device__ __forceinline__ float med3f(float a, float b, float c) {
#if defined(__has_builtin) && __has_builtin(__builtin_amdgcn_fmed3f)
    return __builtin_amdgcn_fmed3f(a, b, c);
#else
    return fmaxf(fminf(fmaxf(a, b), c), fminf(a, b));
#endif
}

// Bijective XCD swizzle: HW assigns block i to XCD i%8, so
// i -> (i%8)*CHUNK + i/8 gives each XCD a contiguous run of row-quads.
__device__ __forceinline__ int swz(int i) {
    return (i & (NXCD - 1)) * CHUNK + (i >> 3);
}

// One coalesced float4 per row segment; halos come from the LDS exchange.
__device__ __forceinline__ float4 load4(const float* __restrict__ img, int h,
                                        int c0) {
    const int hc = min(max(h, 0), HH - 1);
    return *reinterpret_cast<const float4*>(img + hc * WW + c0);
}

// 4 output rows of 4 contrasts from 6 assembled 6-wide rows (exact 3x3 median).
// Column stage: min3/med3/max3 (fused by backend); pixel stage med3-of-3.
__device__ __forceinline__ void contrast4x4(const float (&W)[NROW][6],
                                            float (&c)[RPB][4]) {
#pragma unroll
    for (int t = 0; t < RPB; ++t) {
        float lo[6], mi[6], hi[6];
#pragma unroll
        for (int j = 0; j < 6; ++j) {
            lo[j] = fminf(fminf(W[t][j], W[t + 1][j]), W[t + 2][j]);
            hi[j] = fmaxf(fmaxf(W[t][j], W[t + 1][j]), W[t + 2][j]);
            mi[j] = med3f(W[t][j], W[t + 1][j], W[t + 2][j]);
        }
#pragma unroll
        for (int i = 0; i < 4; ++i) {
            float mx = fmaxf(fmaxf(lo[i], lo[i + 1]), lo[i + 2]);
            float md = med3f(mi[i], mi[i + 1], mi[i + 2]);
            float mn = fminf(fminf(hi[i], hi[i + 1]), hi[i + 2]);
            c[t][i] = W[t + 1][i + 1] - med3f(mx, md, mn);
        }
    }
}

// Assemble 6 six-wide rows from quads + LDS-exchanged halos; zero image edges.
__device__ __forceinline__ void mkwin(const float4 (&v)[NROW],
                                      const float2 (*edge)[BLOCK], int base,
                                      int tl, int tr, bool lz, bool rz,
                                      bool topz, bool botz, float (&W)[NROW][6]) {
#pragma unroll
    for (int r = 0; r < NROW; ++r) {
        W[r][0] = lz ? 0.f : edge[base + r][tl].y;
        W[r][1] = v[r].x; W[r][2] = v[r].y; W[r][3] = v[r].z; W[r][4] = v[r].w;
        W[r][5] = rz ? 0.f : edge[base + r][tr].x;
    }
    if (topz) {
#pragma unroll
        for (int j = 0; j < 6; ++j) W[0][j] = 0.f;
    }
    if (botz) {
#pragma unroll
        for (int j = 0; j < 6; ++j) W[NROW - 1][j] = 0.f;
    }
}

__device__ __forceinline__ float waveRed(float v) {
#pragma unroll
    for (int o = 32; o > 0; o >>= 1) v += __shfl_down(v, o, 64);
    return v;
}

// LDS edge exchange: 12 row-slots (P0..P5, T0..T5) x {v.x, v.w} = 30 KB.

// Pass 1: per-image sums of {mask, mask*|pc|, mask*|tc|} over a row-quad.
__global__ __launch_bounds__(BLOCK) void pass1(const float* __restrict__ pred,
                                               const float* __restrict__ tgt,
                                               const float* __restrict__ mask,
                                               float4* __restrict__ p1s4) {
    const int f  = swz(blockIdx.x);
    const int b  = f / SLOTSI;
    const int rb = f - b * SLOTSI;
    const int h0 = rb * RPB;
    const int q  = threadIdx.x;
    const int c0 = min(q * 4, WW - 4);
    const bool qv = q < QPR;

    const float* pimg = pred + b * IMG;
    const float* timg = tgt  + b * IMG;

    float4 vp[NROW], vt[NROW], m4[RPB];
#pragma unroll
    for (int r = 0; r < NROW; ++r) {
        vp[r] = load4(pimg, h0 - 1 + r, c0);
        vt[r] = load4(timg, h0 - 1 + r, c0);
    }
    const float* mrow = mask + b * IMG + h0 * WW + c0;
#pragma unroll
    for (int r = 0; r < RPB; ++r)
        m4[r] = *reinterpret_cast<const float4*>(mrow + r * WW);
    __builtin_amdgcn_sched_barrier(0);   // all 16 global loads in flight

    __shared__ float2 edge[2 * NROW][BLOCK];
#pragma unroll
    for (int r = 0; r < NROW; ++r) {
        edge[r][q]        = make_float2(vp[r].x, vp[r].w);
        edge[r + NROW][q] = make_float2(vt[r].x, vt[r].w);
    }
    __syncthreads();

    const int tl = max(q - 1, 0), tr = min(q + 1, BLOCK - 1);
    const bool lz = (q == 0), rz = (q >= QPR - 1);
    const bool topz = (h0 == 0), botz = (h0 + RPB == HH);

    float W[NROW][6], pc[RPB][4], tc[RPB][4];
    mkwin(vp, edge, 0, tl, tr, lz, rz, topz, botz, W);
    contrast4x4(W, pc);
    mkwin(vt, edge, NROW, tl, tr, lz, rz, topz, botz, W);
    contrast4x4(W, tc);

    float s_m = 0.f, s_p = 0.f, s_t = 0.f;
#pragma unroll
    for (int r = 0; r < RPB; ++r) {
        float mv[4] = {m4[r].x, m4[r].y, m4[r].z, m4[r].w};
#pragma unroll
        for (int k = 0; k < 4; ++k) {
            s_m += mv[k];
            s_p += mv[k] * fabsf(pc[r][k]);
            s_t += mv[k] * fabsf(tc[r][k]);
        }
    }
    if (!qv) { s_m = 0.f; s_p = 0.f; s_t = 0.f; }

    s_m = waveRed(s_m); s_p = waveRed(s_p); s_t = waveRed(s_t);

    __shared__ float red[3][NWAVE];
    const int lane = threadIdx.x & 63, wid = threadIdx.x >> 6;
    if (lane == 0) { red[0][wid] = s_m; red[1][wid] = s_p; red[2][wid] = s_t; }
    __syncthreads();
    if (threadIdx.x == 0) {
        float a0 = 0.f, a1 = 0.f, a2 = 0.f;
#pragma unroll
        for (int w = 0; w < NWAVE; ++w) { a0 += red[0][w]; a1 += red[1][w]; a2 += red[2][w]; }
        p1s4[b * PADS + rb] = make_float4(a0, a1, a2, 0.f);
        if (rb < PADS - SLOTSI)   // zero-fill pad slots so folds are uniform
            p1s4[b * PADS + SLOTSI + rb] = make_float4(0.f, 0.f, 0.f, 0.f);
    }
}

// Pass 2: per-image sum of |pc*inv_mp - tc*inv_mt| over a row-quad.
// Each wave redundantly folds its image's 128 p1s slots -> no mid kernel.
__global__ __launch_bounds__(BLOCK) void pass2(const float* __restrict__ pred,
                                               const float* __restrict__ tgt,
                                               const float4* __restrict__ p1s4,
                                               float* __restrict__ acc) {
    const int f  = swz(blockIdx.x);
    const int b  = f / SLOTSI;
    const int rb = f - b * SLOTSI;
    const int h0 = rb * RPB;
    const int q  = threadIdx.x;
    const int c0 = min(q * 4, WW - 4);
    const bool qv = q < QPR;
    const int lane = threadIdx.x & 63;

    const float4* s4 = p1s4 + b * PADS;
    float4 f0 = s4[lane];
    float4 f1 = s4[lane + 64];

    const float* pimg = pred + b * IMG;
    const float* timg = tgt  + b * IMG;

    float4 vp[NROW], vt[NROW];
#pragma unroll
    for (int r = 0; r < NROW; ++r) {
        vp[r] = load4(pimg, h0 - 1 + r, c0);
        vt[r] = load4(timg, h0 - 1 + r, c0);
    }
    __builtin_amdgcn_sched_barrier(0);   // all 14 global loads in flight

    __shared__ float2 edge[2 * NROW][BLOCK];
#pragma unroll
    for (int r = 0; r < NROW; ++r) {
        edge[r][q]        = make_float2(vp[r].x, vp[r].w);
        edge[r + NROW][q] = make_float2(vt[r].x, vt[r].w);
    }

    // Fold while the edge exchange settles (independent of LDS).
    float sm = f0.x + f1.x;
    float sp = f0.y + f1.y;
    float st = f0.z + f1.z;
#pragma unroll
    for (int o = 32; o > 0; o >>= 1) {
        sm += __shfl_xor(sm, o, 64);
        sp += __shfl_xor(sp, o, 64);
        st += __shfl_xor(st, o, 64);
    }
    const float inv_mp = sm / sp;
    const float inv_mt = sm / st;
    __syncthreads();

    const int tl = max(q - 1, 0), tr = min(q + 1, BLOCK - 1);
    const bool lz = (q == 0), rz = (q >= QPR - 1);
    const bool topz = (h0 == 0), botz = (h0 + RPB == HH);

    float W[NROW][6], pc[RPB][4], tc[RPB][4];
    mkwin(vp, edge, 0, tl, tr, lz, rz, topz, botz, W);
    contrast4x4(W, pc);
    mkwin(vt, edge, NROW, tl, tr, lz, rz, topz, botz, W);
    contrast4x4(W, tc);

    float s = 0.f;
#pragma unroll
    for (int r = 0; r < RPB; ++r)
#pragma unroll
        for (int k = 0; k < 4; ++k)
            s += fabsf(pc[r][k] * inv_mp - tc[r][k] * inv_mt);
    if (!qv) s = 0.f;

    s = waveRed(s);

    __shared__ float red[NWAVE];
    const int wid = threadIdx.x >> 6;
    if (lane == 0) red[wid] = s;
    __syncthreads();
    if (threadIdx.x == 0) {
        float a = 0.f;
#pragma unroll
        for (int w = 0; w < NWAVE; ++w) a += red[w];
        acc[b * PADS + rb] = a;
        if (rb < PADS - SLOTSI)
            acc[b * PADS + SLOTSI + rb] = 0.f;
    }
}

__global__ __launch_bounds__(BLOCK) void finalize(const float4* __restrict__ p1s4,
                                                  const float* __restrict__ acc,
                                                  float* __restrict__ out) {
    float tm = 0.f, ta = 0.f;
    for (int j = threadIdx.x; j < BATCH * PADS; j += BLOCK) {
        tm += p1s4[j].x;
        ta += acc[j];
    }
    tm = waveRed(tm); ta = waveRed(ta);
    __shared__ float r0[NWAVE], r1[NWAVE];
    const int lane = threadIdx.x & 63, wid = threadIdx.x >> 6;
    if (lane == 0) { r0[wid] = tm; r1[wid] = ta; }
    __syncthreads();
    if (threadIdx.x == 0) {
        float m = 0.f, a = 0.f;
#pragma unroll
        for (int w = 0; w < NWAVE; ++w) { m += r0[w]; a += r1[w]; }
        out[0] = a / m;
    }
}

extern "C" void kernel_launch(void* const* d_in, const int* in_sizes, int n_in,
                              void* d_out, int out_size, void* d_ws, size_t ws_size,
                              hipStream_t stream) {
    const float* pred = (const float*)d_in[0];
    const float* tgt  = (const float*)d_in[1];
    const float* mask = (const float*)d_in[2];
    float* out = (float*)d_out;
    float* ws  = (float*)d_ws;
    float4* p1s4 = (float4*)ws;
    float*  acc  = ws + WS_ACC_F;

    // No memset needed: every workspace slot (incl. pads) is plain-stored.
    dim3 grid(NBLK), blk(BLOCK);
    pass1<<<grid, blk, 0, stream>>>(pred, tgt, mask, p1s4);
    pass2<<<grid, blk, 0, stream>>>(pred, tgt, p1s4, acc);
    finalize<<<1, blk, 0, stream>>>(p1s4, acc, out);
}

// Round 7
// 121.044 us; speedup vs baseline: 1.0378x; 1.0378x over previous
//
#include <hip/hip_runtime.h>

// Geometry fixed by setup_inputs: [16, 1, 352, 1216] fp32.
#define BATCH 16
#define HH    352
#define WW    1216
#define IMG   (HH * WW)
#define QPR   (WW / 4)          // 304 quads (float4 groups) per row
#define RPB   4                 // output rows per wave
#define NROW  (RPB + 2)         // 6 input rows per tensor
#define RQI   (HH / RPB)        // 88 row-quads per image
#define CWPR  5                 // column-waves per row (5*64 quads >= 304)
#define SPI   (RQI * CWPR)      // 440 wave-slots per image
#define SPAD  448               // padded to 7*64 (pads zero-filled)
#define WPB   4                 // waves per block (fully independent waves)
#define BLOCK (WPB * 64)
#define NWAVES (BATCH * SPI)    // 7040
#define NBLK  (NWAVES / WPB)    // 1760 (divisible by 8)
#define NXCD  8
#define CHUNK (NBLK / NXCD)     // 220

// Workspace (floats): [0 .. 28671] p1s = float4[16*448] {Sm,Sp,St,0};
//                     [28672 .. 35839] acc = float[16*448] loss partials.
#define WS_ACC_F (BATCH * SPAD * 4)

__device__ __forceinline__ float med3f(float a, float b, float c) {
#if defined(__has_builtin) && __has_builtin(__builtin_amdgcn_fmed3f)
    return __builtin_amdgcn_fmed3f(a, b, c);
#else
    return fmaxf(fminf(fmaxf(a, b), c), fminf(a, b));
#endif
}

// Bijective XCD swizzle: HW assigns block i to XCD i%8, so
// i -> (i%8)*CHUNK + i/8 gives each XCD a contiguous run of row-quads.
__device__ __forceinline__ int swz(int i) {
    return (i & (NXCD - 1)) * CHUNK + (i >> 3);
}

// One coalesced float4 per row segment (row-clamped; edges zeroed later).
__device__ __forceinline__ float4 load4(const float* __restrict__ img, int h,
                                        int c0) {
    const int hc = min(max(h, 0), HH - 1);
    return *reinterpret_cast<const float4*>(img + hc * WW + c0);
}

// Assemble 6 six-wide rows: in-wave halos via shfl_up/down; wave-boundary
// halos via broadcast shuffles of the 12-lane halo gather register.
// NO LDS, NO barrier — waves stay fully independent.
__device__ __forceinline__ void mkwin(const float4 (&v)[NROW], float halo,
                                      int lane, bool lz, bool rz,
                                      bool topz, bool botz,
                                      float (&W)[NROW][6]) {
#pragma unroll
    for (int r = 0; r < NROW; ++r) {
        float vL = __shfl_up(v[r].w, 1, 64);    // left neighbor's col3
        float vR = __shfl_down(v[r].x, 1, 64);  // right neighbor's col0
        float hL = __shfl(halo, r, 64);         // lane r holds left halo row r
        float hR = __shfl(halo, r + 6, 64);     // lane r+6 holds right halo
        W[r][0] = lz ? 0.f : ((lane == 0)  ? hL : vL);
        W[r][1] = v[r].x; W[r][2] = v[r].y; W[r][3] = v[r].z; W[r][4] = v[r].w;
        W[r][5] = rz ? 0.f : ((lane == 63) ? hR : vR);
    }
    if (topz) {
#pragma unroll
        for (int j = 0; j < 6; ++j) W[0][j] = 0.f;
    }
    if (botz) {
#pragma unroll
        for (int j = 0; j < 6; ++j) W[NROW - 1][j] = 0.f;
    }
}

// 4 output rows of 4 contrasts from the 6 assembled rows (exact 3x3 median).
__device__ __forceinline__ void contrast4x4(const float (&W)[NROW][6],
                                            float (&c)[RPB][4]) {
#pragma unroll
    for (int t = 0; t < RPB; ++t) {
        float lo[6], mi[6], hi[6];
#pragma unroll
        for (int j = 0; j < 6; ++j) {
            lo[j] = fminf(fminf(W[t][j], W[t + 1][j]), W[t + 2][j]);
            hi[j] = fmaxf(fmaxf(W[t][j], W[t + 1][j]), W[t + 2][j]);
            mi[j] = med3f(W[t][j], W[t + 1][j], W[t + 2][j]);
        }
#pragma unroll
        for (int i = 0; i < 4; ++i) {
            float mx = fmaxf(fmaxf(lo[i], lo[i + 1]), lo[i + 2]);
            float md = med3f(mi[i], mi[i + 1], mi[i + 2]);
            float mn = fminf(fminf(hi[i], hi[i + 1]), hi[i + 2]);
            c[t][i] = W[t + 1][i + 1] - med3f(mx, md, mn);
        }
    }
}

__device__ __forceinline__ float waveRed(float v) {
#pragma unroll
    for (int o = 32; o > 0; o >>= 1) v += __shfl_down(v, o, 64);
    return v;
}

// Pass 1: per-image sums of {mask, mask*|pc|, mask*|tc|}; one wave per
// (row-quad, 64-quad column span); per-wave reduce; plain store to own slot.
__global__ __launch_bounds__(BLOCK, 4) void pass1(const float* __restrict__ pred,
                                                  const float* __restrict__ tgt,
                                                  const float* __restrict__ mask,
                                                  float4* __restrict__ p1s4) {
    const int wid  = threadIdx.x >> 6, lane = threadIdx.x & 63;
    const int g    = swz(blockIdx.x) * WPB + wid;
    const int rq   = g / CWPR, cw = g - rq * CWPR;
    const int b    = rq / RQI,  rb = rq - b * RQI;
    const int h0   = rb * RPB;
    const int gq   = cw * 64 + lane;
    const int c0   = min(gq * 4, WW - 4);
    const bool qv  = gq < QPR;

    const float* pimg = pred + b * IMG;
    const float* timg = tgt  + b * IMG;

    float4 vp[NROW], vt[NROW], m4[RPB];
#pragma unroll
    for (int r = 0; r < NROW; ++r) vp[r] = load4(pimg, h0 - 1 + r, c0);
    float hp = 0.f, ht = 0.f;
    int haddr = 0;
    if (lane < 12) {                      // 12-lane halo gather (1 instr/tensor)
        const int r   = (lane < 6) ? lane : lane - 6;
        const int hc  = min(max(h0 - 1 + r, 0), HH - 1);
        const int col = (lane < 6) ? max(cw * 256 - 1, 0)
                                   : min(cw * 256 + 256, WW - 1);
        haddr = hc * WW + col;
        hp = pimg[haddr];
    }
#pragma unroll
    for (int r = 0; r < NROW; ++r) vt[r] = load4(timg, h0 - 1 + r, c0);
    if (lane < 12) ht = timg[haddr];
    const float* mrow = mask + b * IMG + h0 * WW + c0;
#pragma unroll
    for (int r = 0; r < RPB; ++r)
        m4[r] = *reinterpret_cast<const float4*>(mrow + r * WW);
    __builtin_amdgcn_sched_barrier(0);    // all loads issued before compute

    const bool lz = (c0 == 0), rz = (c0 + 4 >= WW);
    const bool topz = (rb == 0), botz = (rb == RQI - 1);

    // pred stage waits only its own loads (vmcnt partial) — tgt+mask in flight
    float W[NROW][6], pc[RPB][4], tc[RPB][4];
    mkwin(vp, hp, lane, lz, rz, topz, botz, W);
    contrast4x4(W, pc);
    mkwin(vt, ht, lane, lz, rz, topz, botz, W);
    contrast4x4(W, tc);

    float s_m = 0.f, s_p = 0.f, s_t = 0.f;
#pragma unroll
    for (int r = 0; r < RPB; ++r) {
        float mv[4] = {m4[r].x, m4[r].y, m4[r].z, m4[r].w};
#pragma unroll
        for (int k = 0; k < 4; ++k) {
            s_m += mv[k];
            s_p += mv[k] * fabsf(pc[r][k]);
            s_t += mv[k] * fabsf(tc[r][k]);
        }
    }
    if (!qv) { s_m = 0.f; s_p = 0.f; s_t = 0.f; }

    s_m = waveRed(s_m); s_p = waveRed(s_p); s_t = waveRed(s_t);

    const int s = rb * CWPR + cw;
    if (lane == 0) {
        p1s4[b * SPAD + s] = make_float4(s_m, s_p, s_t, 0.f);
        if (s < SPAD - SPI)               // zero-fill the 8 pad slots
            p1s4[b * SPAD + SPI + s] = make_float4(0.f, 0.f, 0.f, 0.f);
    }
}

// Pass 2: per-image sum of |pc*inv_mp - tc*inv_mt|. Fold loads issue FIRST
// so the per-wave p1s fold runs while the stencil loads are in flight.
__global__ __launch_bounds__(BLOCK, 4) void pass2(const float* __restrict__ pred,
                                                  const float* __restrict__ tgt,
                                                  const float4* __restrict__ p1s4,
                                                  float* __restrict__ acc) {
    const int wid  = threadIdx.x >> 6, lane = threadIdx.x & 63;
    const int g    = swz(blockIdx.x) * WPB + wid;
    const int rq   = g / CWPR, cw = g - rq * CWPR;
    const int b    = rq / RQI,  rb = rq - b * RQI;
    const int h0   = rb * RPB;
    const int gq   = cw * 64 + lane;
    const int c0   = min(gq * 4, WW - 4);
    const bool qv  = gq < QPR;

    const float4* s4 = p1s4 + b * SPAD;
    float4 fv[7];
#pragma unroll
    for (int k = 0; k < 7; ++k) fv[k] = s4[lane + k * 64];

    const float* pimg = pred + b * IMG;
    const float* timg = tgt  + b * IMG;

    float4 vp[NROW], vt[NROW];
#pragma unroll
    for (int r = 0; r < NROW; ++r) vp[r] = load4(pimg, h0 - 1 + r, c0);
    float hp = 0.f, ht = 0.f;
    int haddr = 0;
    if (lane < 12) {
        const int r   = (lane < 6) ? lane : lane - 6;
        const int hc  = min(max(h0 - 1 + r, 0), HH - 1);
        const int col = (lane < 6) ? max(cw * 256 - 1, 0)
                                   : min(cw * 256 + 256, WW - 1);
        haddr = hc * WW + col;
        hp = pimg[haddr];
    }
#pragma unroll
    for (int r = 0; r < NROW; ++r) vt[r] = load4(timg, h0 - 1 + r, c0);
    if (lane < 12) ht = timg[haddr];
    __builtin_amdgcn_sched_barrier(0);    // all loads issued before compute

    // Fold waits only the 7 oldest loads; stencil stays in flight.
    float sm = 0.f, sp = 0.f, st = 0.f;
#pragma unroll
    for (int k = 0; k < 7; ++k) { sm += fv[k].x; sp += fv[k].y; st += fv[k].z; }
#pragma unroll
    for (int o = 32; o > 0; o >>= 1) {
        sm += __shfl_xor(sm, o, 64);
        sp += __shfl_xor(sp, o, 64);
        st += __shfl_xor(st, o, 64);
    }
    const float inv_mp = sm / sp;
    const float inv_mt = sm / st;

    const bool lz = (c0 == 0), rz = (c0 + 4 >= WW);
    const bool topz = (rb == 0), botz = (rb == RQI - 1);

    float W[NROW][6], pc[RPB][4], tc[RPB][4];
    mkwin(vp, hp, lane, lz, rz, topz, botz, W);
    contrast4x4(W, pc);
    mkwin(vt, ht, lane, lz, rz, topz, botz, W);
    contrast4x4(W, tc);

    float s = 0.f;
#pragma unroll
    for (int r = 0; r < RPB; ++r)
#pragma unroll
        for (int k = 0; k < 4; ++k)
            s += fabsf(pc[r][k] * inv_mp - tc[r][k] * inv_mt);
    if (!qv) s = 0.f;

    s = waveRed(s);

    const int sl = rb * CWPR + cw;
    if (lane == 0) {
        acc[b * SPAD + sl] = s;
        if (sl < SPAD - SPI)
            acc[b * SPAD + SPI + sl] = 0.f;
    }
}

__global__ __launch_bounds__(1024) void finalize(const float4* __restrict__ p1s4,
                                                 const float* __restrict__ acc,
                                                 float* __restrict__ out) {
    float tm = 0.f, ta = 0.f;
    for (int j = threadIdx.x; j < BATCH * SPAD; j += 1024) {
        tm += p1s4[j].x;
        ta += acc[j];
    }
    tm = waveRed(tm); ta = waveRed(ta);
    __shared__ float r0[16], r1[16];
    const int lane = threadIdx.x & 63, wid = threadIdx.x >> 6;
    if (lane == 0) { r0[wid] = tm; r1[wid] = ta; }
    __syncthreads();
    if (threadIdx.x == 0) {
        float m = 0.f, a = 0.f;
#pragma unroll
        for (int w = 0; w < 16; ++w) { m += r0[w]; a += r1[w]; }
        out[0] = a / m;
    }
}

extern "C" void kernel_launch(void* const* d_in, const int* in_sizes, int n_in,
                              void* d_out, int out_size, void* d_ws, size_t ws_size,
                              hipStream_t stream) {
    const float* pred = (const float*)d_in[0];
    const float* tgt  = (const float*)d_in[1];
    const float* mask = (const float*)d_in[2];
    float* out = (float*)d_out;
    float* ws  = (float*)d_ws;
    float4* p1s4 = (float4*)ws;
    float*  acc  = ws + WS_ACC_F;

    // No memset needed: every workspace slot (incl. pads) is plain-stored.
    dim3 grid(NBLK), blk(BLOCK);
    pass1<<<grid, blk, 0, stream>>>(pred, tgt, mask, p1s4);
    pass2<<<grid, blk, 0, stream>>>(pred, tgt, p1s4, acc);
    finalize<<<1, 1024, 0, stream>>>(p1s4, acc, out);
}